// Round 1
// baseline (1175.531 us; speedup 1.0000x reference)
//
#include <hip/hip_runtime.h>
#include <hip/hip_bf16.h>
#include <math.h>

// Problem constants (fixed by the reference setup_inputs)
#define BB 32
#define PP 24564
#define OO 16
#define CC 81
#define BP (BB * PP)

__device__ __forceinline__ float sl1(float x) {
    float ax = fabsf(x);
    return ax < 1.0f ? 0.5f * ax * ax : ax - 0.5f;
}

// ---------------------------------------------------------------------------
// K1: matching. One block per batch. Computes per-prior best-truth overlap/idx
// and per-truth best prior (argmax over P, first-index tie-break), then
// thread 0 applies the sequential override (numpy last-writer-wins).
// ---------------------------------------------------------------------------
__global__ __launch_bounds__(256) void k_match(
        const float* __restrict__ priors, const float* __restrict__ truths,
        float* __restrict__ bto, int* __restrict__ bti) {
    const int b = blockIdx.x;
    const int tid = threadIdx.x;
    __shared__ float tr[OO][4];
    __shared__ float tarea[OO];
    if (tid < OO * 4) ((float*)tr)[tid] = truths[b * OO * 4 + tid];
    __syncthreads();
    if (tid < OO) tarea[tid] = (tr[tid][2] - tr[tid][0]) * (tr[tid][3] - tr[tid][1]);
    __syncthreads();

    float bpv[OO];
    int bpi[OO];
#pragma unroll
    for (int o = 0; o < OO; o++) { bpv[o] = -1.0f; bpi[o] = 0x7fffffff; }

    for (int p = tid; p < PP; p += 256) {
        const float cx = priors[p * 4 + 0], cy = priors[p * 4 + 1];
        const float w  = priors[p * 4 + 2], h  = priors[p * 4 + 3];
        const float x1 = cx - w * 0.5f, y1 = cy - h * 0.5f;
        const float x2 = cx + w * 0.5f, y2 = cy + h * 0.5f;
        const float parea = (x2 - x1) * (y2 - y1);
        float best = -1.0f;
        int bidx = 0;
#pragma unroll
        for (int o = 0; o < OO; o++) {
            const float lx = fmaxf(tr[o][0], x1), ly = fmaxf(tr[o][1], y1);
            const float rx = fminf(tr[o][2], x2), ry = fminf(tr[o][3], y2);
            const float iw = fmaxf(rx - lx, 0.0f), ih = fmaxf(ry - ly, 0.0f);
            const float inter = iw * ih;
            const float iou = inter / (tarea[o] + parea - inter);
            if (iou > best) { best = iou; bidx = o; }          // first-max over o
            if (iou > bpv[o]) { bpv[o] = iou; bpi[o] = p; }    // p ascending per thread
        }
        bto[(size_t)b * PP + p] = best;
        bti[(size_t)b * PP + p] = bidx;
    }

    __shared__ float rv[OO][256];
    __shared__ int   ri[OO][256];
#pragma unroll
    for (int o = 0; o < OO; o++) { rv[o][tid] = bpv[o]; ri[o][tid] = bpi[o]; }
    __syncthreads();
    __shared__ int bp[OO];
    if (tid < OO) {
        float v = rv[tid][0];
        int ix = ri[tid][0];
        for (int t = 1; t < 256; t++) {
            const float vv = rv[tid][t];
            const int ii = ri[tid][t];
            if (vv > v || (vv == v && ii < ix)) { v = vv; ix = ii; }
        }
        bp[tid] = ix;
    }
    __syncthreads();
    if (tid == 0) {
        // numpy fancy-assignment semantics: later o overrides earlier on dup idx
        for (int o = 0; o < OO; o++) {
            const int p = bp[o];
            bto[(size_t)b * PP + p] = 2.0f;
            bti[(size_t)b * PP + p] = o;
        }
    }
}

// ---------------------------------------------------------------------------
// K2: one wave (64 lanes) per (b,p) row. Wave logsumexp over 81 conf logits;
// lane 0 handles obj ce, mining writes, and positive-row loc loss + pos CE.
// acc layout: [0]=loss_l [1]=pos_ce_obj [2]=pos_ce_c [3]=neg_obj [4]=neg_c
// ---------------------------------------------------------------------------
__global__ __launch_bounds__(256) void k_ce(
        const float* __restrict__ conf, const float* __restrict__ obj,
        const float* __restrict__ loc, const float* __restrict__ priors,
        const float* __restrict__ truths, const int* __restrict__ labels,
        const float* __restrict__ bto, const int* __restrict__ bti,
        float* __restrict__ mining_obj, float* __restrict__ mining_c,
        int* __restrict__ num_pos, float* __restrict__ acc) {
    const int lane = threadIdx.x & 63;
    const int row = blockIdx.x * 4 + (threadIdx.x >> 6);
    if (row >= BP) return;
    const int b = row / PP;
    const int p = row - b * PP;
    const size_t base = (size_t)row * CC;

    const float x0 = (lane < CC) ? conf[base + lane] : -INFINITY;
    const float x1 = (lane + 64 < CC) ? conf[base + lane + 64] : -INFINITY;
    float m = fmaxf(x0, x1);
#pragma unroll
    for (int off = 32; off; off >>= 1) m = fmaxf(m, __shfl_xor(m, off));
    float s = 0.0f;
    if (lane < CC) s += expf(x0 - m);
    if (lane + 64 < CC) s += expf(x1 - m);
#pragma unroll
    for (int off = 32; off; off >>= 1) s += __shfl_xor(s, off);
    const float lse_c = m + logf(s);

    if (lane == 0) {
        const float ov = bto[row];
        const int ti = bti[row];
        const int lbl = labels[b * OO + ti];
        const int tgt = (ov < 0.5f) ? 0 : lbl;
        const float ce_c = lse_c - conf[base + tgt];

        const float o0 = obj[(size_t)row * 2 + 0];
        const float o1 = obj[(size_t)row * 2 + 1];
        const float mo = fmaxf(o0, o1);
        const float lse_o = mo + logf(expf(o0 - mo) + expf(o1 - mo));
        const bool pos = tgt > 0;
        const float ce_o = lse_o - (pos ? o1 : o0);

        mining_c[row]   = pos ? 0.0f : ce_c;
        mining_obj[row] = pos ? 0.0f : ce_o;

        if (pos) {
            atomicAdd(&num_pos[b], 1);
            atomicAdd(&acc[1], ce_o);
            atomicAdd(&acc[2], ce_c);
            const float* pr = priors + (size_t)p * 4;
            const float* t  = truths + ((size_t)b * OO + ti) * 4;
            const float mx1 = t[0], my1 = t[1], mx2 = t[2], my2 = t[3];
            const float pcx = pr[0], pcy = pr[1], pw = pr[2], ph = pr[3];
            const float gcx = ((mx1 + mx2) * 0.5f - pcx) / (0.1f * pw);
            const float gcy = ((my1 + my2) * 0.5f - pcy) / (0.1f * ph);
            const float gw = logf((mx2 - mx1) / pw) / 0.2f;
            const float gh = logf((my2 - my1) / ph) / 0.2f;
            const float* ld = loc + (size_t)row * 4;
            const float l = sl1(ld[0] - gcx) + sl1(ld[1] - gcy) +
                            sl1(ld[2] - gw) + sl1(ld[3] - gh);
            atomicAdd(&acc[0], l);
        }
    }
}

// ---------------------------------------------------------------------------
// K3: top-k sum via 4-pass byte radix-select. 64 blocks: {obj,c} x 32 batches.
// mining values are nonnegative floats -> uint bit order == float order.
// ---------------------------------------------------------------------------
__global__ __launch_bounds__(256) void k_select(
        const float* __restrict__ mining /* [2][B][P] */,
        const int* __restrict__ num_pos, float* __restrict__ acc,
        int* __restrict__ n1_acc) {
    const int arr = blockIdx.x >> 5;  // 0 = obj, 1 = c
    const int b = blockIdx.x & 31;
    const float* x = mining + ((size_t)arr * BB + b) * PP;
    const int np = num_pos[b];
    long long k64 = 3LL * np;
    const int k = (int)(k64 < (long long)(PP - 1) ? k64 : (long long)(PP - 1));
    if (threadIdx.x == 0 && arr == 0) atomicAdd(n1_acc, k);
    if (k <= 0) return;

    __shared__ unsigned hist[256];
    __shared__ unsigned s_prefix;
    __shared__ int s_krem;
    if (threadIdx.x == 0) { s_prefix = 0u; s_krem = k; }
    __syncthreads();

    for (int shift = 24; shift >= 0; shift -= 8) {
        hist[threadIdx.x] = 0u;
        __syncthreads();
        const unsigned prefix = s_prefix;
        const unsigned pmask = (shift == 24) ? 0u : (0xFFFFFFFFu << (shift + 8));
        for (int i = threadIdx.x; i < PP; i += 256) {
            const unsigned u = __float_as_uint(x[i]);
            if ((u & pmask) == prefix)
                atomicAdd(&hist[(u >> shift) & 255u], 1u);
        }
        __syncthreads();
        if (threadIdx.x == 0) {
            const int krem = s_krem;
            unsigned cum = 0;
            int sel = 0;
            for (int byte = 255; byte >= 0; byte--) {
                const unsigned h = hist[byte];
                if (cum + h >= (unsigned)krem) { sel = byte; break; }
                cum += h;
            }
            s_krem = krem - (int)cum;
            s_prefix = prefix | ((unsigned)sel << shift);
        }
        __syncthreads();
    }

    const unsigned t = s_prefix;
    float lsum = 0.0f;
    unsigned lcnt = 0;
    for (int i = threadIdx.x; i < PP; i += 256) {
        const float v = x[i];
        if (__float_as_uint(v) > t) { lsum += v; lcnt++; }
    }
    __shared__ float sred[256];
    __shared__ unsigned cred[256];
    sred[threadIdx.x] = lsum;
    cred[threadIdx.x] = lcnt;
    __syncthreads();
    for (int st = 128; st; st >>= 1) {
        if (threadIdx.x < st) {
            sred[threadIdx.x] += sred[threadIdx.x + st];
            cred[threadIdx.x] += cred[threadIdx.x + st];
        }
        __syncthreads();
    }
    if (threadIdx.x == 0) {
        const float tsum = sred[0] + (float)(k - (int)cred[0]) * __uint_as_float(t);
        atomicAdd(&acc[3 + arr], tsum);
    }
}

// ---------------------------------------------------------------------------
// K4: final scalars.
// ---------------------------------------------------------------------------
__global__ void k_final(const float* __restrict__ acc,
                        const int* __restrict__ num_pos,
                        const int* __restrict__ n1_acc,
                        float* __restrict__ out) {
    if (threadIdx.x == 0 && blockIdx.x == 0) {
        int N = 0;
        for (int b = 0; b < BB; b++) N += num_pos[b];
        const float fN = (float)(N > 1 ? N : 1);
        const int n1 = *n1_acc;
        const float fN1 = (float)(n1 > 1 ? n1 : 1);
        out[0] = acc[0] / fN;
        out[1] = (acc[2] + acc[4]) / fN;
        out[2] = 0.4f * (acc[1] + acc[3]) / fN1;
    }
}

extern "C" void kernel_launch(void* const* d_in, const int* in_sizes, int n_in,
                              void* d_out, int out_size, void* d_ws, size_t ws_size,
                              hipStream_t stream) {
    const float* loc_data  = (const float*)d_in[0];
    const float* conf_data = (const float*)d_in[1];
    const float* obj_data  = (const float*)d_in[2];
    const float* priors    = (const float*)d_in[3];
    const float* truths    = (const float*)d_in[4];
    const int*   labels    = (const int*)d_in[5];
    float* out = (float*)d_out;

    // Workspace layout (floats):
    // [0, BP)          bto
    // [BP, 2BP)        bti (int)
    // [2BP, 4BP)       mining: [0]=obj, [1]=c
    // [4BP, ...)       num_pos (32 ints), acc (8 floats), n1 (int)
    float* ws_f = (float*)d_ws;
    float* bto = ws_f;
    int*   bti = (int*)(ws_f + BP);
    float* mining = ws_f + 2 * (size_t)BP;      // 2*BP floats
    int*   num_pos = (int*)(ws_f + 4 * (size_t)BP);
    float* acc = ws_f + 4 * (size_t)BP + 32;    // 5 floats used
    int*   n1_acc = (int*)(ws_f + 4 * (size_t)BP + 48);

    // zero the small accumulator region (num_pos + acc + n1)
    hipMemsetAsync((void*)num_pos, 0, 256, stream);

    k_match<<<BB, 256, 0, stream>>>(priors, truths, bto, bti);

    const int rows_per_block = 4;  // 4 waves of 64
    const int nblk = (BP + rows_per_block - 1) / rows_per_block;
    k_ce<<<nblk, 256, 0, stream>>>(conf_data, obj_data, loc_data, priors, truths,
                                   labels, bto, bti,
                                   mining /*obj*/, mining + BP /*c*/,
                                   num_pos, acc);

    k_select<<<64, 256, 0, stream>>>(mining, num_pos, acc, n1_acc);

    k_final<<<1, 64, 0, stream>>>(acc, num_pos, n1_acc, out);
}

// Round 2
// 821.741 us; speedup vs baseline: 1.4305x; 1.4305x over previous
//
#include <hip/hip_runtime.h>
#include <hip/hip_bf16.h>
#include <math.h>

// Problem constants (fixed by the reference setup_inputs)
#define BB 32
#define PP 24564
#define OO 16
#define CC 81
#define BP (BB * PP)
#define CHUNK 1024   // priors per k_match_a block; ceil(PP/CHUNK)=24 chunks

typedef unsigned long long ull;

__device__ __forceinline__ float sl1(float x) {
    float ax = fabsf(x);
    return ax < 1.0f ? 0.5f * ax * ax : ax - 0.5f;
}

// ---------------------------------------------------------------------------
// K1a: matching, parallel over (chunk, batch). Computes per-prior best-truth
// (bto/bti) and per-truth best-prior via packed-key atomicMax:
//   key = (iou_bits << 32) | (0xFFFFFFFF - p)   -> max iou, tie: smallest p
// ---------------------------------------------------------------------------
__global__ __launch_bounds__(256) void k_match_a(
        const float* __restrict__ priors, const float* __restrict__ truths,
        float* __restrict__ bto, int* __restrict__ bti,
        ull* __restrict__ best_prior /* [BB][OO], pre-zeroed */) {
    const int b = blockIdx.y;
    const int p0 = blockIdx.x * CHUNK;
    const int tid = threadIdx.x;
    __shared__ float tr[OO][4];
    __shared__ float tarea[OO];
    __shared__ ull red[OO];
    if (tid < OO * 4) ((float*)tr)[tid] = truths[b * OO * 4 + tid];
    if (tid < OO) red[tid] = 0ull;
    __syncthreads();
    if (tid < OO) tarea[tid] = (tr[tid][2] - tr[tid][0]) * (tr[tid][3] - tr[tid][1]);
    __syncthreads();

    float bpv[OO];
    int bpi[OO];
#pragma unroll
    for (int o = 0; o < OO; o++) { bpv[o] = -1.0f; bpi[o] = -1; }

    const int pend = (p0 + CHUNK < PP) ? p0 + CHUNK : PP;
    for (int p = p0 + tid; p < pend; p += 256) {
        const float4 pr = ((const float4*)priors)[p];
        const float x1 = pr.x - pr.z * 0.5f, y1 = pr.y - pr.w * 0.5f;
        const float x2 = pr.x + pr.z * 0.5f, y2 = pr.y + pr.w * 0.5f;
        const float parea = (x2 - x1) * (y2 - y1);
        float best = -1.0f;
        int bidx = 0;
#pragma unroll
        for (int o = 0; o < OO; o++) {
            const float lx = fmaxf(tr[o][0], x1), ly = fmaxf(tr[o][1], y1);
            const float rx = fminf(tr[o][2], x2), ry = fminf(tr[o][3], y2);
            const float iw = fmaxf(rx - lx, 0.0f), ih = fmaxf(ry - ly, 0.0f);
            const float inter = iw * ih;
            const float iou = inter / (tarea[o] + parea - inter);
            if (iou > best) { best = iou; bidx = o; }          // first-max over o
            if (iou > bpv[o]) { bpv[o] = iou; bpi[o] = p; }    // p ascending per thread
        }
        bto[(size_t)b * PP + p] = best;
        bti[(size_t)b * PP + p] = bidx;
    }

#pragma unroll
    for (int o = 0; o < OO; o++) {
        if (bpi[o] >= 0) {
            const ull key = ((ull)__float_as_uint(bpv[o]) << 32) |
                            (ull)(0xFFFFFFFFu - (unsigned)bpi[o]);
            atomicMax(&red[o], key);
        }
    }
    __syncthreads();
    if (tid < OO && red[tid] != 0ull)
        atomicMax(&best_prior[b * OO + tid], red[tid]);
}

// K1b: sequential (numpy last-writer-wins) override, one thread per batch.
__global__ void k_match_b(const ull* __restrict__ best_prior,
                          float* __restrict__ bto, int* __restrict__ bti) {
    const int b = threadIdx.x;
    if (b >= BB) return;
    for (int o = 0; o < OO; o++) {
        const unsigned p = 0xFFFFFFFFu - (unsigned)(best_prior[b * OO + o] & 0xFFFFFFFFull);
        bto[(size_t)b * PP + p] = 2.0f;
        bti[(size_t)b * PP + p] = o;
    }
}

// ---------------------------------------------------------------------------
// K2: tile of 64 rows per block, staged through LDS with coalesced float4
// loads. LSE by 4 threads/row; epilogue by 64 threads with conf[tgt] gather
// served from LDS. acc: [0]=loss_l [1]=pos_ce_obj [2]=pos_ce_c [3]=neg_obj
// [4]=neg_c
// ---------------------------------------------------------------------------
__global__ __launch_bounds__(256) void k_ce(
        const float* __restrict__ conf, const float* __restrict__ obj,
        const float* __restrict__ loc, const float* __restrict__ priors,
        const float* __restrict__ truths, const int* __restrict__ labels,
        const float* __restrict__ bto, const int* __restrict__ bti,
        float* __restrict__ mining_obj, float* __restrict__ mining_c,
        int* __restrict__ num_pos, float* __restrict__ acc) {
    const int tid = threadIdx.x;
    const int row0 = blockIdx.x * 64;            // BP == 64 * gridDim.x exactly
    __shared__ float sconf[64 * CC];             // 20736 B
    __shared__ float slse[64];

    const float4* src = (const float4*)(conf + (size_t)row0 * CC);
    float4* dst = (float4*)sconf;
    for (int i = tid; i < (64 * CC) / 4; i += 256) dst[i] = src[i];
    __syncthreads();

    const int r = tid >> 2;
    const int part = tid & 3;
    const float* rowp = sconf + r * CC;
    const int c0 = part * 20;
    const int c1 = (part == 3) ? CC : c0 + 20;   // 20,20,20,21
    float m = -INFINITY;
    for (int c = c0; c < c1; c++) m = fmaxf(m, rowp[c]);
    m = fmaxf(m, __shfl_xor(m, 1));
    m = fmaxf(m, __shfl_xor(m, 2));
    float s = 0.0f;
    for (int c = c0; c < c1; c++) s += __expf(rowp[c] - m);
    s += __shfl_xor(s, 1);
    s += __shfl_xor(s, 2);
    if (part == 0) slse[r] = m + __logf(s);
    __syncthreads();

    if (tid < 64) {
        const int row = row0 + tid;
        const int b = row / PP;
        const int p = row - b * PP;
        const float ov = bto[row];
        const int ti = bti[row];
        const int lbl = labels[b * OO + ti];
        const int tgt = (ov < 0.5f) ? 0 : lbl;
        const float ce_c = slse[tid] - sconf[tid * CC + tgt];

        const float2 o2 = ((const float2*)obj)[row];
        const float mo = fmaxf(o2.x, o2.y);
        const float lse_o = mo + __logf(__expf(o2.x - mo) + __expf(o2.y - mo));
        const bool pos = tgt > 0;
        const float ce_o = lse_o - (pos ? o2.y : o2.x);

        mining_c[row]   = pos ? 0.0f : ce_c;
        mining_obj[row] = pos ? 0.0f : ce_o;

        if (pos) {
            atomicAdd(&num_pos[b], 1);
            atomicAdd(&acc[1], ce_o);
            atomicAdd(&acc[2], ce_c);
            const float4 pr = ((const float4*)priors)[p];
            const float4 t  = ((const float4*)truths)[b * OO + ti];
            const float gcx = ((t.x + t.z) * 0.5f - pr.x) / (0.1f * pr.z);
            const float gcy = ((t.y + t.w) * 0.5f - pr.y) / (0.1f * pr.w);
            const float gw = logf((t.z - t.x) / pr.z) / 0.2f;
            const float gh = logf((t.w - t.y) / pr.w) / 0.2f;
            const float4 ld = ((const float4*)loc)[row];
            const float l = sl1(ld.x - gcx) + sl1(ld.y - gcy) +
                            sl1(ld.z - gw) + sl1(ld.w - gh);
            atomicAdd(&acc[0], l);
        }
    }
}

// ---------------------------------------------------------------------------
// K3: top-k sum via 4-pass byte radix-select. 64 blocks: {obj,c} x 32 batches.
// ---------------------------------------------------------------------------
__global__ __launch_bounds__(256) void k_select(
        const float* __restrict__ mining /* [2][B][P] */,
        const int* __restrict__ num_pos, float* __restrict__ acc,
        int* __restrict__ n1_acc) {
    const int arr = blockIdx.x >> 5;  // 0 = obj, 1 = c
    const int b = blockIdx.x & 31;
    const float* x = mining + ((size_t)arr * BB + b) * PP;
    const int np = num_pos[b];
    long long k64 = 3LL * np;
    const int k = (int)(k64 < (long long)(PP - 1) ? k64 : (long long)(PP - 1));
    if (threadIdx.x == 0 && arr == 0) atomicAdd(n1_acc, k);
    if (k <= 0) return;

    __shared__ unsigned hist[256];
    __shared__ unsigned s_prefix;
    __shared__ int s_krem;
    if (threadIdx.x == 0) { s_prefix = 0u; s_krem = k; }
    __syncthreads();

    for (int shift = 24; shift >= 0; shift -= 8) {
        hist[threadIdx.x] = 0u;
        __syncthreads();
        const unsigned prefix = s_prefix;
        const unsigned pmask = (shift == 24) ? 0u : (0xFFFFFFFFu << (shift + 8));
        for (int i = threadIdx.x; i < PP; i += 256) {
            const unsigned u = __float_as_uint(x[i]);
            if ((u & pmask) == prefix)
                atomicAdd(&hist[(u >> shift) & 255u], 1u);
        }
        __syncthreads();
        if (threadIdx.x == 0) {
            const int krem = s_krem;
            unsigned cum = 0;
            int sel = 0;
            for (int byte = 255; byte >= 0; byte--) {
                const unsigned h = hist[byte];
                if (cum + h >= (unsigned)krem) { sel = byte; break; }
                cum += h;
            }
            s_krem = krem - (int)cum;
            s_prefix = prefix | ((unsigned)sel << shift);
        }
        __syncthreads();
    }

    const unsigned t = s_prefix;
    float lsum = 0.0f;
    unsigned lcnt = 0;
    for (int i = threadIdx.x; i < PP; i += 256) {
        const float v = x[i];
        if (__float_as_uint(v) > t) { lsum += v; lcnt++; }
    }
    __shared__ float sred[256];
    __shared__ unsigned cred[256];
    sred[threadIdx.x] = lsum;
    cred[threadIdx.x] = lcnt;
    __syncthreads();
    for (int st = 128; st; st >>= 1) {
        if (threadIdx.x < st) {
            sred[threadIdx.x] += sred[threadIdx.x + st];
            cred[threadIdx.x] += cred[threadIdx.x + st];
        }
        __syncthreads();
    }
    if (threadIdx.x == 0) {
        const float tsum = sred[0] + (float)(k - (int)cred[0]) * __uint_as_float(t);
        atomicAdd(&acc[3 + arr], tsum);
    }
}

// K4: final scalars.
__global__ void k_final(const float* __restrict__ acc,
                        const int* __restrict__ num_pos,
                        const int* __restrict__ n1_acc,
                        float* __restrict__ out) {
    if (threadIdx.x == 0 && blockIdx.x == 0) {
        int N = 0;
        for (int b = 0; b < BB; b++) N += num_pos[b];
        const float fN = (float)(N > 1 ? N : 1);
        const int n1 = *n1_acc;
        const float fN1 = (float)(n1 > 1 ? n1 : 1);
        out[0] = acc[0] / fN;
        out[1] = (acc[2] + acc[4]) / fN;
        out[2] = 0.4f * (acc[1] + acc[3]) / fN1;
    }
}

extern "C" void kernel_launch(void* const* d_in, const int* in_sizes, int n_in,
                              void* d_out, int out_size, void* d_ws, size_t ws_size,
                              hipStream_t stream) {
    const float* loc_data  = (const float*)d_in[0];
    const float* conf_data = (const float*)d_in[1];
    const float* obj_data  = (const float*)d_in[2];
    const float* priors    = (const float*)d_in[3];
    const float* truths    = (const float*)d_in[4];
    const int*   labels    = (const int*)d_in[5];
    float* out = (float*)d_out;

    // Workspace layout (floats):
    // [0, BP)            bto
    // [BP, 2BP)          bti (int)
    // [2BP, 4BP)         mining: [0]=obj, [1]=c
    // [4BP, 4BP+1024)    best_prior: 512 ull (zeroed)
    // [4BP+1024, ...)    num_pos (32 int), acc (8 f), n1 (int)  (zeroed)
    float* ws_f = (float*)d_ws;
    float* bto = ws_f;
    int*   bti = (int*)(ws_f + BP);
    float* mining = ws_f + 2 * (size_t)BP;
    ull*   best_prior = (ull*)(ws_f + 4 * (size_t)BP);
    int*   num_pos = (int*)(ws_f + 4 * (size_t)BP + 1024);
    float* acc = ws_f + 4 * (size_t)BP + 1024 + 32;
    int*   n1_acc = (int*)(ws_f + 4 * (size_t)BP + 1024 + 48);

    // zero best_prior + num_pos + acc + n1 in one shot
    hipMemsetAsync((void*)best_prior, 0, 8192, stream);

    dim3 mg((PP + CHUNK - 1) / CHUNK, BB);
    k_match_a<<<mg, 256, 0, stream>>>(priors, truths, bto, bti, best_prior);
    k_match_b<<<1, 32, 0, stream>>>(best_prior, bto, bti);

    k_ce<<<BP / 64, 256, 0, stream>>>(conf_data, obj_data, loc_data, priors,
                                      truths, labels, bto, bti,
                                      mining /*obj*/, mining + BP /*c*/,
                                      num_pos, acc);

    k_select<<<64, 256, 0, stream>>>(mining, num_pos, acc, n1_acc);

    k_final<<<1, 64, 0, stream>>>(acc, num_pos, n1_acc, out);
}